// Round 9
// baseline (874.570 us; speedup 1.0000x reference)
//
#include <hip/hip_runtime.h>
#include <math.h>
#include <stdint.h>

// Problem dims (fixed by setup_inputs)
#define B_N 256
#define C_N 1152
#define I_N 8
#define N_N 10
#define D_N 16

typedef short v8s __attribute__((ext_vector_type(8)));   // 8 bf16 (4 VGPRs) MFMA A/B frag
typedef float v4f __attribute__((ext_vector_type(4)));   // 4 f32 MFMA C/D frag

__device__ __forceinline__ uint32_t bf16_rne(float f) {
    uint32_t u = __float_as_uint(f);
    return (u + 0x7FFFu + ((u >> 16) & 1u)) >> 16;
}
__device__ __forceinline__ uint32_t pack2(float a, float b) {
    return bf16_rne(a) | (bf16_rne(b) << 16);
}
__device__ __forceinline__ float blo(uint32_t u) { return __uint_as_float(u << 16); }
__device__ __forceinline__ float bhi(uint32_t u) { return __uint_as_float(u & 0xffff0000u); }

// ============================ K1: u_hat materialization =====================
// u_hat[b][n][d][c] bf16 (94 MB in d_ws). Per block: 16 b x 16 c chunk, all n.
// MFMA sweep1 pattern (proven R5-R8): per (c,n) K-padded 16x16x32 -> u[d,b] frag;
// frags transposed through LDS ubuf[b][d][c] -> coalesced 32B-row global drain.
constexpr int POOL1 = 40960 + 4352 + 8448;  // 53760 B -> 3 blocks/CU

__global__ __launch_bounds__(256, 3)
void uhat_kernel(const float* __restrict__ x, const float* __restrict__ W,
                 short* __restrict__ uh)
{
    __shared__ __align__(16) char pool[POOL1];
    short* Wsl  = (short*)pool;              // [16c][10n][128], c-stride 1280
    short* xsl  = (short*)(pool + 40960);    // [16b][136] (16c*8i + 8 pad)
    short* ubuf = (short*)(pool + 45312);    // [16b][16d][16c], b-stride 264

    const int tid  = threadIdx.x;
    const int wv   = tid >> 6;
    const int lane = tid & 63;
    const int m    = lane & 15;    // A-row (=d) for A-frag; D-col (=b) for D-frag
    const int quad = lane >> 4;
    const int c0   = blockIdx.x * 16;
    const int gb0  = blockIdx.y * 16;

    // stage x[gb0..+16][c0..+16][8i] f32 -> bf16
    {
        const float4* x4 = (const float4*)x;
        #pragma unroll
        for (int it = 0; it < 2; ++it) {
            int e = (tid + 256 * it) * 4;            // < 2048
            int b2 = e >> 7, r = e & 127;
            float4 v = x4[((gb0 + b2) * 9216 + (c0 + (r >> 3)) * 8 + (r & 7)) >> 2];
            *(uint2*)(xsl + b2 * 136 + r) = make_uint2(pack2(v.x, v.y), pack2(v.z, v.w));
        }
    }
    // stage W[n][c0..+16][16d][8i] f32 -> bf16
    {
        const float4* W4 = (const float4*)W;
        #pragma unroll
        for (int it = 0; it < 20; ++it) {
            int e = (tid + 256 * it) * 4;            // < 20480
            int n = e >> 11, rr = e & 2047;
            int c = rr >> 7, k = rr & 127;
            float4 v = W4[n * 36864 + (c0 + c) * 32 + (k >> 2)];
            *(uint2*)(Wsl + c * 1280 + n * 128 + k) = make_uint2(pack2(v.x, v.y), pack2(v.z, v.w));
        }
    }
    __syncthreads();

    for (int n = 0; n < N_N; ++n) {
        #pragma unroll
        for (int j = 0; j < 4; ++j) {
            const int cl = wv + 4 * j;
            v8s wa = {0, 0, 0, 0, 0, 0, 0, 0};
            if (quad == 0)    // only k=0..7 real; rest zero-pad kills k>=8
                wa = *(const v8s*)(Wsl + cl * 1280 + n * 128 + m * 8);
            const v8s xb = *(const v8s*)(xsl + m * 136 + cl * 8);
            v4f u = __builtin_amdgcn_mfma_f32_16x16x32_bf16(wa, xb, (v4f){0.f, 0.f, 0.f, 0.f}, 0, 0, 0);
            #pragma unroll
            for (int r = 0; r < 4; ++r)   // D: col=m(=b), row=quad*4+r(=d)
                ubuf[m * 264 + (quad * 4 + r) * 16 + cl] = (short)bf16_rne(u[r]);
        }
        __syncthreads();
        {   // drain: thread (bb,dd) -> 32B row u_hat[b][n][d][c0..c0+15]
            const int bb = tid >> 4, dd = tid & 15;
            uint4 a0 = *(const uint4*)(ubuf + bb * 264 + dd * 16);
            uint4 a1 = *(const uint4*)(ubuf + bb * 264 + dd * 16 + 8);
            size_t dst = ((size_t)((gb0 + bb) * 10 + n) * 16 + dd) * 1152 + c0;
            *(uint4*)(uh + dst) = a0;
            *(uint4*)(uh + dst + 8) = a1;
        }
        __syncthreads();
    }
}

// ============================ K2: fused 3-pass routing ======================
// One block per b (512 thr = 8 waves). All routing state block-local:
//   v_lds (current vsum for logits), coef (softmax coefs), stot/redq (s totals).
// Phase1 (p>0): waves own c-ranges (72 pairs each); per c-pair compute 10 logits
//   from u.v (f32), softmax (no max-sub, |l|<~3 proven R3-R8), coef -> LDS.
// Phase2: waves own n (wv=full n; n=8,9 split in c-quarters over wave halves);
//   s[d] accumulates per lane over c, 64-lane butterfly, squash by threads<160.
// coef pre-filled 0.1 so pass 0 reuses the generic phase2.
constexpr int CP_STRIDE = 584;   // float2 per n row (576 + pad)

__global__ __launch_bounds__(512, 2)
void routing_kernel(const short* __restrict__ uh, float* __restrict__ out)
{
    __shared__ __align__(16) float2 coef[10 * CP_STRIDE];   // 46720 B
    __shared__ float v_lds[160];
    __shared__ float stot[160];
    __shared__ float redq[128];

    const int tid  = threadIdx.x;
    const int wv   = tid >> 6;
    const int lane = tid & 63;
    const int b    = blockIdx.x;
    const uint* U  = (const uint*)uh;            // dword = 2 adjacent c's
    const int qn    = (wv < 4) ? 8 : 9;
    const int qbase = (wv & 3) * 144;

    for (int i = tid; i < 10 * CP_STRIDE; i += 512)
        coef[i] = make_float2(0.1f, 0.1f);
    __syncthreads();

    for (int p = 0; p < 3; ++p) {
        if (p > 0) {
            // ---- phase 1: logits + softmax for this wave's 72 c-pairs ----
            #pragma unroll
            for (int it = 0; it < 2; ++it) {
                const int P = wv * 72 + it * 64 + lane;
                const bool act = (it == 0) | (lane < 8);
                if (act) {
                    float ex[10], ey[10];
                    float Zx = 0.f, Zy = 0.f;
                    #pragma unroll
                    for (int n = 0; n < 10; ++n) {
                        float lx = 0.f, ly = 0.f;
                        const int rb = ((b * 10 + n) * 16) * 576 + P;
                        #pragma unroll
                        for (int dq = 0; dq < 4; ++dq) {
                            const float4 vv = *(const float4*)(v_lds + n * 16 + dq * 4);
                            const float vs[4] = {vv.x, vv.y, vv.z, vv.w};
                            #pragma unroll
                            for (int r = 0; r < 4; ++r) {
                                const uint u2 = U[rb + (dq * 4 + r) * 576];
                                lx = fmaf(blo(u2), vs[r], lx);
                                ly = fmaf(bhi(u2), vs[r], ly);
                            }
                        }
                        ex[n] = __expf(lx); ey[n] = __expf(ly);
                        Zx += ex[n]; Zy += ey[n];
                    }
                    const float rx = __builtin_amdgcn_rcpf(Zx);
                    const float ry = __builtin_amdgcn_rcpf(Zy);
                    #pragma unroll
                    for (int n = 0; n < 10; ++n)
                        coef[n * CP_STRIDE + P] = make_float2(ex[n] * rx, ey[n] * ry);
                }
            }
        }
        __syncthreads();   // coef ready

        // ---- phase 2: s accumulation (wave-owned n) ----
        float sf[16], sq_[16];
        #pragma unroll
        for (int d = 0; d < 16; ++d) { sf[d] = 0.f; sq_[d] = 0.f; }
        // full n = wv over all 576 pairs (9 exact iters)
        for (int it = 0; it < 9; ++it) {
            const int P = it * 64 + lane;
            const float2 cf = coef[wv * CP_STRIDE + P];
            const int rb = ((b * 10 + wv) * 16) * 576 + P;
            #pragma unroll
            for (int d = 0; d < 16; ++d) {
                const uint u2 = U[rb + d * 576];
                sf[d] += cf.x * blo(u2) + cf.y * bhi(u2);
            }
        }
        // quarter of n=8 or 9 (144 pairs: 64+64+16)
        #pragma unroll
        for (int it = 0; it < 3; ++it) {
            const int P = qbase + it * 64 + lane;
            const bool act = (it < 2) | (lane < 16);
            if (act) {
                const float2 cf = coef[qn * CP_STRIDE + P];
                const int rb = ((b * 10 + qn) * 16) * 576 + P;
                #pragma unroll
                for (int d = 0; d < 16; ++d) {
                    const uint u2 = U[rb + d * 576];
                    sq_[d] += cf.x * blo(u2) + cf.y * bhi(u2);
                }
            }
        }
        // 64-lane butterfly (inactive lanes contributed zeros)
        #pragma unroll
        for (int off = 1; off < 64; off <<= 1) {
            #pragma unroll
            for (int d = 0; d < 16; ++d) {
                sf[d]  += __shfl_xor(sf[d], off);
                sq_[d] += __shfl_xor(sq_[d], off);
            }
        }
        if (lane == 0) {
            #pragma unroll
            for (int d = 0; d < 16; ++d) {
                stot[wv * 16 + d] = sf[d];
                redq[wv * 16 + d] = sq_[d];
            }
        }
        __syncthreads();

        // ---- squash + v update (threads < 160; 16-lane groups stay in-wave) ----
        if (tid < 160) {
            const int n = tid >> 4, d = tid & 15;
            float sv;
            if (n < 8)      sv = stot[tid];
            else if (n == 8) sv = redq[d] + redq[16 + d] + redq[32 + d] + redq[48 + d];
            else             sv = redq[64 + d] + redq[80 + d] + redq[96 + d] + redq[112 + d];
            float ss = sv * sv;
            ss += __shfl_xor(ss, 1); ss += __shfl_xor(ss, 2);
            ss += __shfl_xor(ss, 4); ss += __shfl_xor(ss, 8);
            const float scale = (ss / (1.f + ss)) / (sqrtf(ss) + 1e-8f);
            const float vnew = scale * sv;
            if (p == 2)      out[b * 160 + tid] = vnew;           // final v
            else if (p == 0) v_lds[tid] = vnew;                   // vsum = v0
            else             v_lds[tid] = v_lds[tid] + vnew;      // vsum += v1
        }
        __syncthreads();
    }
}

extern "C" void kernel_launch(void* const* d_in, const int* in_sizes, int n_in,
                              void* d_out, int out_size, void* d_ws, size_t ws_size,
                              hipStream_t stream)
{
    const float* x = (const float*)d_in[0];
    const float* W = (const float*)d_in[1];
    float* out = (float*)d_out;
    short* uh  = (short*)d_ws;   // u_hat bf16 [256][10][16][1152] = 94 MB

    uhat_kernel<<<dim3(72, 16), 256, 0, stream>>>(x, W, uh);
    routing_kernel<<<dim3(256), 512, 0, stream>>>(uh, out);
}

// Round 10
// 130.360 us; speedup vs baseline: 6.7089x; 6.7089x over previous
//
#include <hip/hip_runtime.h>
#include <math.h>
#include <stdint.h>

// Problem dims (fixed by setup_inputs)
#define B_N 256
#define C_N 1152
#define I_N 8
#define N_N 10
#define D_N 16

constexpr int C_PER    = 18;             // c's per route block
constexpr int C_CHUNKS = C_N / C_PER;    // 64
constexpr int STAGE_C  = 6;              // c's per W staging round
constexpr int N_STAGES = 3;
constexpr int BLOCK    = 256;
// route grid = 64 x 16 = 1024 blocks = exactly 4 blocks/CU

typedef short v8s __attribute__((ext_vector_type(8)));
typedef float v4f __attribute__((ext_vector_type(4)));

// ---- LDS pool (bytes), route_pass ----
//   Ws  (short): [6c][10n][16d][8i] = 15360 @ 0        (DMA, linear)
//   xs  (short): [18c][16b][8i]     =  4608 @ 15360    (DMA, linear)
//   vst (float): [16b][164]         = 10496 @ 19968    (DMA, linear, padded rows)
//   cfl (float): [6c][163]          =  3912 @ 30464
//   rz  (float): [6c][16b]          =   384 @ 34376
//   comb(float): [16b][164] ALIASES Ws                 @ 0
constexpr int POOL_BYTES = 34760;   // -> 4 blocks/CU

// ws layout (floats unless noted):
//   vstG: [16 btile][16 b][164]            = 41984 fl  (168 KB)
//   p_s : [64 chunk][256 b][160]           = 2.62M fl  (10.5 MB)
//   Wb  : short [1152 c][10 n][128]        = 1.47M sh  (2.95 MB)
//   xt  : short [1024 tile][18 c][16 b][8] = 2.36M sh  (4.7 MB)
constexpr size_t VSTG_FL = 16 * 16 * 164;
constexpr size_t PS_FL   = (size_t)C_CHUNKS * B_N * 160;
constexpr size_t WB_SH   = (size_t)C_N * 1280;
constexpr size_t XT_SH   = (size_t)1024 * 2304;

#define GLD16(g, l)                                                         \
    __builtin_amdgcn_global_load_lds(                                       \
        (const uint32_t __attribute__((address_space(1)))*)(g),             \
        (uint32_t __attribute__((address_space(3)))*)(l), 16, 0, 0)

__device__ __forceinline__ uint32_t bf16_rne(float f) {
    uint32_t u = __float_as_uint(f);
    return (u + 0x7FFFu + ((u >> 16) & 1u)) >> 16;
}
__device__ __forceinline__ uint32_t pack2(float a, float b) {
    return bf16_rne(a) | (bf16_rne(b) << 16);
}
__device__ __forceinline__ float bf2f(short s) {
    return __uint_as_float(((uint32_t)(uint16_t)s) << 16);
}

// ---- K0a: W fp32 -> bf16, layout [c][n][16d*8i] ----
__global__ __launch_bounds__(BLOCK)
void conv_w(const float* __restrict__ W, short* __restrict__ Wb)
{
    const int c0 = blockIdx.x * 8;
    const int cc = threadIdx.x >> 5;        // 8 c's per block
    const int k4 = threadIdx.x & 31;        // 32 float4 per (n,c)
    const float4* W4 = (const float4*)W;
    uint2* dst = (uint2*)Wb;
    for (int n = 0; n < N_N; ++n) {
        float4 v = W4[(size_t)n * 36864 + (size_t)(c0 + cc) * 32 + k4];
        dst[(((size_t)(c0 + cc) * 1280 + n * 128) >> 2) + k4] =
            make_uint2(pack2(v.x, v.y), pack2(v.z, v.w));
    }
}

// ---- K0b: x fp32 -> bf16 per-route-block tiles [tile][18c][16b][8i] ----
__global__ __launch_bounds__(BLOCK)
void conv_x(const float* __restrict__ x, short* __restrict__ xt)
{
    const int tile  = blockIdx.x;            // chunk*16 + btile
    const int chunk = tile >> 4;
    const int btile = tile & 15;
    const int c0    = chunk * C_PER;
    const int gb0   = btile * 16;
    const float4* x4 = (const float4*)x;
    uint2* dst = (uint2*)(xt + (size_t)tile * 2304);
    #pragma unroll
    for (int it = 0; it < 3; ++it) {
        int f = threadIdx.x + BLOCK * it;    // < 576 float4
        if (f < 576) {
            int b = f / 36, r = f - b * 36;  // r: 36 float4 per b (18c*8i)
            float4 v = x4[(size_t)(gb0 + b) * 2304 + c0 * 2 + r];
            int cp = r >> 1, i0 = (r & 1) * 4;
            dst[((cp * 128 + b * 8 + i0) >> 2)] =
                make_uint2(pack2(v.x, v.y), pack2(v.z, v.w));
        }
    }
}

// ---- route pass: all staging via global_load_lds (zero staging VALU) ----
// Sweep1: 60 independent (c,n) chains flattened over 4 waves (15 each):
//   K-padded MFMA -> u[d,b]; l = u.vst + 2 shfl; exp -> cfl (unnormalized).
// Z-step: threads<96 sum 10 n's per (c,b), rz = rcp(Z).
// Sweep2: K=32 packs 4c x 8i; B = bf16(cv*x); waves own n-subsets; Q=1 covers
//   c=4,5 only (quads 2,3 zero-padded via wa=0).
template <bool FIRST>
__global__ __launch_bounds__(BLOCK, 4)
void route_pass(const short* __restrict__ Wb, const short* __restrict__ xt,
                const float* __restrict__ vstG, float* __restrict__ p_s)
{
    __shared__ __align__(16) char pool[POOL_BYTES];
    short* Ws   = (short*)pool;
    short* xs   = (short*)(pool + 15360);
    float* vst  = (float*)(pool + 19968);
    float* cfl  = (float*)(pool + 30464);
    float* rz   = (float*)(pool + 34376);
    float* comb = (float*)pool;

    const int tid   = threadIdx.x;
    const int wv    = tid >> 6;
    const int lane  = tid & 63;
    const int b     = lane & 15;   // D-col / B-col; also A-row m (=d)
    const int quad  = lane >> 4;
    const int chunk = blockIdx.x;
    const int btile = blockIdx.y;
    const int gb0   = btile * 16;
    const int c0    = chunk * C_PER;

    // ---- DMA x tile (288 x 16B) and vst tile (656 x 16B) ----
    {
        const char* src = (const char*)(xt + (size_t)(chunk * 16 + btile) * 2304);
        #pragma unroll
        for (int it = 0; it < 2; ++it) {
            int f = tid + BLOCK * it;
            if (f < 288) GLD16(src + f * 16, (char*)xs + f * 16);
        }
    }
    if (!FIRST) {
        const char* src = (const char*)(vstG + (size_t)btile * 2624);
        #pragma unroll
        for (int it = 0; it < 3; ++it) {
            int f = tid + BLOCK * it;
            if (f < 656) GLD16(src + f * 16, (char*)vst + f * 16);
        }
    }

    const int ncnt = (wv < 2) ? 3 : 2;   // wave wv owns n = wv, wv+4, (wv+8)
    v4f sacc[3];
    sacc[0] = (v4f){0.f, 0.f, 0.f, 0.f};
    sacc[1] = (v4f){0.f, 0.f, 0.f, 0.f};
    sacc[2] = (v4f){0.f, 0.f, 0.f, 0.f};

    for (int st = 0; st < N_STAGES; ++st) {
        __syncthreads();   // prev sweep2 done with Ws
        // ---- DMA W stage: 6 c's bf16 = 960 x 16B ----
        {
            const char* src = (const char*)(Wb + (size_t)(c0 + st * STAGE_C) * 1280);
            #pragma unroll
            for (int it = 0; it < 4; ++it) {
                int f = tid + BLOCK * it;
                if (f < 960) GLD16(src + f * 16, (char*)Ws + f * 16);
            }
        }
        __syncthreads();   // drains all DMA (incl. x/vst on st=0)

        if (!FIRST) {
            // ---- sweep1: 15 independent (c,n) chains per wave ----
            #pragma unroll
            for (int k = 0; k < 15; ++k) {
                const int idx = wv + 4 * k;      // < 60
                const int c   = idx / 10;
                const int n   = idx - c * 10;
                v8s wa = {0, 0, 0, 0, 0, 0, 0, 0};
                if (quad == 0)
                    wa = *(const v8s*)(Ws + c * 1280 + n * 128 + b * 8);
                const v8s xb = *(const v8s*)(xs + (st * STAGE_C + c) * 128 + b * 8);
                v4f u = __builtin_amdgcn_mfma_f32_16x16x32_bf16(
                    wa, xb, (v4f){0.f, 0.f, 0.f, 0.f}, 0, 0, 0);
                const float4 v4 = *(const float4*)(vst + b * 164 + n * 16 + quad * 4);
                float l = u[0] * v4.x + u[1] * v4.y + u[2] * v4.z + u[3] * v4.w;
                l += __shfl_xor(l, 16);
                l += __shfl_xor(l, 32);
                const float e1 = __expf(l);      // |l| <~ 3: no max-sub needed
                if (quad == 0) cfl[c * 163 + n * 16 + b] = e1;
            }
            __syncthreads();
            // ---- Z-step: 96 (c,b) sums ----
            if (tid < 96) {
                const int c = tid >> 4, bb = tid & 15;
                float Z = 0.f;
                #pragma unroll
                for (int n = 0; n < N_N; ++n) Z += cfl[c * 163 + n * 16 + bb];
                rz[c * 16 + bb] = __builtin_amdgcn_rcpf(Z);
            }
            __syncthreads();
        }

        // ---- sweep2 ----
        #pragma unroll
        for (int Q = 0; Q < 2; ++Q) {
            const int  clq   = Q * 4 + quad;
            const bool valid = (clq < STAGE_C);
            const int  clql  = valid ? clq : 0;
            const v8s xq = *(const v8s*)(xs + (st * STAGE_C + clql) * 128 + b * 8);
            float xf[8];
            #pragma unroll
            for (int j = 0; j < 8; ++j) xf[j] = bf2f(xq[j]);
            #pragma unroll
            for (int jj = 0; jj < 3; ++jj) {
                if (jj < ncnt) {
                    const int n = wv + 4 * jj;
                    const float cv = FIRST ? 0.1f
                        : cfl[clql * 163 + n * 16 + b] * rz[clql * 16 + b];
                    union { v8s s; uint32_t u[4]; } zu;
                    zu.u[0] = pack2(cv * xf[0], cv * xf[1]);
                    zu.u[1] = pack2(cv * xf[2], cv * xf[3]);
                    zu.u[2] = pack2(cv * xf[4], cv * xf[5]);
                    zu.u[3] = pack2(cv * xf[6], cv * xf[7]);
                    v8s wa = {0, 0, 0, 0, 0, 0, 0, 0};
                    if (valid)
                        wa = *(const v8s*)(Ws + clql * 1280 + n * 128 + b * 8);
                    sacc[jj] = __builtin_amdgcn_mfma_f32_16x16x32_bf16(
                        wa, zu.s, sacc[jj], 0, 0, 0);
                }
            }
        }
    }

    __syncthreads();   // all Ws/xs/cfl reads done -> comb alias safe
    #pragma unroll
    for (int jj = 0; jj < 3; ++jj) {
        if (jj < ncnt) {
            const int n = wv + 4 * jj;
            #pragma unroll
            for (int r = 0; r < 4; ++r)
                comb[b * 164 + n * 16 + quad * 4 + r] = sacc[jj][r];
        }
    }
    __syncthreads();
    #pragma unroll
    for (int it = 0; it < 3; ++it) {
        int f = tid + BLOCK * it;
        if (f < 640) {
            int e = f * 4;
            int bb = e / 160, rem = e - bb * 160;
            float4 v = *(const float4*)(comb + bb * 164 + rem);
            *(float4*)(&p_s[((size_t)chunk * B_N + gb0 + bb) * 160 + rem]) = v;
        }
    }
}

// ---- reduce+squash; writes padded vst tiles for DMA staging ----
__global__ __launch_bounds__(BLOCK)
void reduce_squash(const float* __restrict__ p_s, float* __restrict__ vstG,
                   float* __restrict__ out, int phase)
{
    const int warp = threadIdx.x >> 6;
    const int lane = threadIdx.x & 63;
    const int g    = blockIdx.x * 4 + warp;   // 0..2559 == b*10+n
    const int q    = lane & 3;
    const int h    = lane >> 2;

    float4 s = make_float4(0.f, 0.f, 0.f, 0.f);
    #pragma unroll
    for (int m = 0; m < C_CHUNKS / 16; ++m) {   // 4
        const int cc = h + 16 * m;
        float4 v = *(const float4*)(&p_s[((size_t)cc * (B_N * N_N) + g) * D_N + q * 4]);
        s.x += v.x; s.y += v.y; s.z += v.z; s.w += v.w;
    }
    #pragma unroll
    for (int off = 4; off < 64; off <<= 1) {
        s.x += __shfl_xor(s.x, off);
        s.y += __shfl_xor(s.y, off);
        s.z += __shfl_xor(s.z, off);
        s.w += __shfl_xor(s.w, off);
    }
    float sq = s.x * s.x + s.y * s.y + s.z * s.z + s.w * s.w;
    sq += __shfl_xor(sq, 1);
    sq += __shfl_xor(sq, 2);

    const float scale = (sq / (1.f + sq)) / (sqrtf(sq) + 1e-8f);
    const float4 v = make_float4(scale * s.x, scale * s.y, scale * s.z, scale * s.w);

    if (h == 0) {
        if (phase == 2) {
            *(float4*)(&out[(size_t)g * D_N + q * 4]) = v;
        } else {
            const int bb = g / 10, n = g - bb * 10;
            float* vp = vstG + (size_t)(bb >> 4) * 2624 + (bb & 15) * 164 + n * 16 + q * 4;
            if (phase == 0) {
                *(float4*)vp = v;
            } else {
                float4 o = *(const float4*)vp;
                *(float4*)vp = make_float4(o.x + v.x, o.y + v.y, o.z + v.z, o.w + v.w);
            }
        }
    }
}

extern "C" void kernel_launch(void* const* d_in, const int* in_sizes, int n_in,
                              void* d_out, int out_size, void* d_ws, size_t ws_size,
                              hipStream_t stream)
{
    const float* x = (const float*)d_in[0];
    const float* W = (const float*)d_in[1];
    float* out  = (float*)d_out;

    float* vstG = (float*)d_ws;
    float* p_s  = vstG + VSTG_FL;
    short* Wb   = (short*)(p_s + PS_FL);
    short* xt   = Wb + WB_SH;

    conv_w<<<dim3(C_N / 8), BLOCK, 0, stream>>>(W, Wb);
    conv_x<<<dim3(1024), BLOCK, 0, stream>>>(x, xt);

    dim3 grid(C_CHUNKS, 16);
    dim3 rgrid((B_N * N_N) / 4);

    route_pass<true><<<grid, BLOCK, 0, stream>>>(Wb, xt, vstG, p_s);
    reduce_squash<<<rgrid, BLOCK, 0, stream>>>(p_s, vstG, out, 0);
    route_pass<false><<<grid, BLOCK, 0, stream>>>(Wb, xt, vstG, p_s);
    reduce_squash<<<rgrid, BLOCK, 0, stream>>>(p_s, vstG, out, 1);
    route_pass<false><<<grid, BLOCK, 0, stream>>>(Wb, xt, vstG, p_s);
    reduce_squash<<<rgrid, BLOCK, 0, stream>>>(p_s, vstG, out, 2);
}